// Round 8
// baseline (45.567 us; speedup 1.0000x reference)
//
#include <hip/hip_runtime.h>

#define N_VERT 163842
#define N8_X   1310736              // N_VERT*64/8
#define NBLK   512                  // 2 blocks/CU, one full round
#define ROWS_PER_BLK 320

typedef float  f32x4  __attribute__((ext_vector_type(4)));
typedef short  s16x8  __attribute__((ext_vector_type(8)));

__device__ __forceinline__ unsigned short f2bf(float f) {
  union { float f; unsigned int u; } c; c.f = f;
  unsigned int u = c.u;
  u += 0x7FFFu + ((u >> 16) & 1u);   // RNE truncate to bf16
  return (unsigned short)(u >> 16);
}

__device__ __forceinline__ s16x8 cvt8(const f32x4 a, const f32x4 b) {
  s16x8 h;
  h[0] = (short)f2bf(a[0]); h[1] = (short)f2bf(a[1]);
  h[2] = (short)f2bf(a[2]); h[3] = (short)f2bf(a[3]);
  h[4] = (short)f2bf(b[0]); h[5] = (short)f2bf(b[1]);
  h[6] = (short)f2bf(b[2]); h[7] = (short)f2bf(b[3]);
  return h;
}

__global__ void detect64(const unsigned int* __restrict__ hexw, int* __restrict__ flag) {
  __shared__ int any;
  if (threadIdx.x == 0) any = 0;
  __syncthreads();
  if (hexw[2 * threadIdx.x + 1] != 0u) any = 1;
  __syncthreads();
  if (threadIdx.x == 0) *flag = (any == 0) ? 1 : 0;   // 1 => int64, 0 => int32
}

// Fused prep: per-block is64 detect; W->Wf frag bf16 (blocks 1..112);
// hexT[j*N+v] = byte offset (idx<<7) of gather row (transposed, u32);
// x -> xbf. Wf byte layout: frag(ks,hi,col) at ks*4096 + hi*1024 + col*16.
__global__ __launch_bounds__(256) void prep(
    const float* __restrict__ x, const unsigned int* __restrict__ hexw,
    const float* __restrict__ W,
    unsigned short* __restrict__ Wf, unsigned int* __restrict__ hexT,
    unsigned short* __restrict__ xbf, int* __restrict__ flag)
{
  const int b = blockIdx.x, tid = threadIdx.x;

  // per-block is64 detect (int64 data: odd u32 words all zero, values < 2^18)
  __shared__ int anyb;
  if (tid == 0) anyb = 0;
  __syncthreads();
  if (hexw[2 * tid + 1] != 0u) anyb = 1;
  __syncthreads();
  const int is64 = (anyb == 0) ? 1 : 0;
  if (b == 0 && tid == 0) *flag = is64;

  if (b >= 1 && b <= 112) {                  // 112*256 = 28672 = 448*64
    const int t   = (b - 1) * 256 + tid;
    const int e   = t & 7;
    const int col = (t >> 3) & 63;
    const int hi  = (t >> 9) & 3;
    const int ks  = t >> 11;
    Wf[t] = f2bf(W[(ks * 32 + hi * 8 + e) * 64 + col]);
  }

  const int stride = gridDim.x * 256;

  // hexT: coalesced writes, strided reads of hex (4.6/9.2 MB, L2-friendly)
  const int T7 = 7 * N_VERT;
  for (int t = b * 256 + tid; t < T7; t += stride) {
    const int j = t / N_VERT;
    const int v = t - j * N_VERT;
    const unsigned int idx = hexw[(unsigned int)(v * 7 + j) << is64];
    hexT[t] = idx << 7;                      // byte offset into xbf (128 B rows)
  }

  for (int i = b * 256 + tid; i < N8_X; i += stride) {
    const f32x4* s = (const f32x4*)(x + (size_t)i * 8);
    *(s16x8*)(xbf + (size_t)i * 8) = cvt8(s[0], s[1]);
  }
}

// ---------------- fallback (no workspace): R7 kernel, f32 direct ----------------
template <int BF>
__global__ __launch_bounds__(256) void hexconv7(
    const void* __restrict__ xsrc, const unsigned int* __restrict__ hexw,
    const void* __restrict__ wsrc, const float* __restrict__ bias,
    float* __restrict__ out, const int* __restrict__ flag)
{
  __shared__ unsigned short Wl[28672];
  const int tid = threadIdx.x;
  const int wv  = tid >> 6;
  const int ln  = tid & 63;
  const int lo  = ln & 15;
  const int hi  = ln >> 4;
  const int is64 = flag ? *flag : 1;

  {
    const float* W = (const float*)wsrc;
    for (int it = 0; it < 112; ++it) {
      const int t   = it * 256 + tid;
      const int e   = t & 7;
      const int col = (t >> 3) & 63;
      const int hif = (t >> 9) & 3;
      const int ks  = t >> 11;
      Wl[t] = f2bf(W[(ks * 32 + hif * 8 + e) * 64 + col]);
    }
  }
  __syncthreads();

  const char* xbase = (const char*)xsrc;
  const char* hexb  = (const char*)hexw;
  const char* Wb    = (const char*)Wl + (hi * 64 + lo) * 16;

  float bval[4];
#pragma unroll
  for (int nt = 0; nt < 4; ++nt) bval[nt] = bias[nt * 16 + lo];

  const int B0 = blockIdx.x * ROWS_PER_BLK;
  const int base3 = (wv < 2) ? wv * 96 : 192 + (wv - 2) * 64;
  const int rb0 = B0 + base3;
  const int rb1 = rb0 + 32;
  const bool special = (blockIdx.x == NBLK - 1) && (wv == 2);
  const bool three = (wv < 2) || special;
  const int rb2 = special ? 163840 : rb0 + 64;
  const int shf = 2 + is64;

  f32x4 acc0[4], acc1[4];
  for (int cc = 0; cc < 3; ++cc) {
    if (cc == 2 && !three) break;
    const int rb = (cc == 0) ? rb0 : (cc == 1) ? rb1 : rb2;
#pragma unroll
    for (int nt = 0; nt < 4; ++nt) { acc0[nt] = (f32x4){0,0,0,0}; acc1[nt] = (f32x4){0,0,0,0}; }
    int ra = rb + lo;        ra = (ra < N_VERT) ? ra : (N_VERT - 1);
    int rbx = rb + 16 + lo;  rbx = (rbx < N_VERT) ? rbx : (N_VERT - 1);
    const char* ipa = hexb + ((size_t)((unsigned)ra * 7u) << shf);
    const char* ipb = hexb + ((size_t)((unsigned)rbx * 7u) << shf);
#pragma unroll
    for (int j = 0; j < 7; ++j) {
      const size_t o0 = (size_t)(*(const unsigned int*)(ipa + ((size_t)j << shf))) << 8;
      const size_t o1 = (size_t)(*(const unsigned int*)(ipb + ((size_t)j << shf))) << 8;
      const char* p0 = xbase + o0;
      const char* p1 = xbase + o1;
      const f32x4* q0 = (const f32x4*)(p0 + hi * 32);
      const f32x4* q1 = (const f32x4*)(p1 + hi * 32);
      const s16x8 a00 = cvt8(q0[0], q0[1]);
      const s16x8 a01 = cvt8(*(const f32x4*)(p0 + 128 + hi * 32), *(const f32x4*)(p0 + 144 + hi * 32));
      const s16x8 a10 = cvt8(q1[0], q1[1]);
      const s16x8 a11 = cvt8(*(const f32x4*)(p1 + 128 + hi * 32), *(const f32x4*)(p1 + 144 + hi * 32));
#pragma unroll
      for (int nt = 0; nt < 4; ++nt) {
        const s16x8 bf0 = *(const s16x8*)(Wb + (2 * j) * 4096 + nt * 256);
        acc0[nt] = __builtin_amdgcn_mfma_f32_16x16x32_bf16(a00, bf0, acc0[nt], 0, 0, 0);
        acc1[nt] = __builtin_amdgcn_mfma_f32_16x16x32_bf16(a10, bf0, acc1[nt], 0, 0, 0);
      }
#pragma unroll
      for (int nt = 0; nt < 4; ++nt) {
        const s16x8 bf1 = *(const s16x8*)(Wb + (2 * j + 1) * 4096 + nt * 256);
        acc0[nt] = __builtin_amdgcn_mfma_f32_16x16x32_bf16(a01, bf1, acc0[nt], 0, 0, 0);
        acc1[nt] = __builtin_amdgcn_mfma_f32_16x16x32_bf16(a11, bf1, acc1[nt], 0, 0, 0);
      }
    }
#pragma unroll
    for (int i = 0; i < 4; ++i) {
      const int row0 = rb + hi * 4 + i;
      if (row0 < N_VERT) {
        float* orow = out + (size_t)row0 * 64;
#pragma unroll
        for (int nt = 0; nt < 4; ++nt) orow[nt * 16 + lo] = acc0[nt][i] + bval[nt];
      }
      const int row1 = rb + 16 + hi * 4 + i;
      if (row1 < N_VERT) {
        float* orow = out + (size_t)row1 * 64;
#pragma unroll
        for (int nt = 0; nt < 4; ++nt) orow[nt * 16 + lo] = acc1[nt][i] + bval[nt];
      }
    }
  }
}

// ---------------- R8 main: quad-contiguous gather + swizzled LDS bounce ----------------
__global__ __launch_bounds__(256) void hexconv8(
    const unsigned short* __restrict__ xbf,
    const unsigned int* __restrict__ hexT,   // [j*N + v] byte offsets
    const unsigned short* __restrict__ Wf,
    const float* __restrict__ bias,
    float* __restrict__ out)
{
  __shared__ unsigned short Wl[28672];         // 57344 B
  __shared__ unsigned int   offsb[4][2][224];  // 7168 B: per-wave, chunk-parity, [j*32+r]
  __shared__ unsigned short bounce[4][2048];   // 16384 B: per-wave 32 rows x 128 B (swizzled)

  const int tid = threadIdx.x;
  const int wv  = tid >> 6;
  const int ln  = tid & 63;
  const int lo  = ln & 15;
  const int hi  = ln >> 4;
  const int oct = ln >> 3;          // gather: row within octet group
  const int qr16 = (ln & 7) * 16;   // gather: 16B segment within row (ADJACENT lanes!)

  // stage W into LDS (frag layout)
  {
    const s16x8* wsv = (const s16x8*)Wf;
#pragma unroll
    for (int it = 0; it < 14; ++it)
      ((s16x8*)Wl)[it * 256 + tid] = wsv[it * 256 + tid];
  }
  __syncthreads();                  // the only barrier

  const char* xbase = (const char*)xbf;
  const char* Wb    = (const char*)Wl + (hi * 64 + lo) * 16;
  char*       bnc   = (char*)&bounce[wv][0];
  char*       bncw  = bnc + oct * 128 + (qr16 ^ (oct << 4));   // swizzled write base
  const int   rswz  = (lo & 7) << 4;
  const int   fb0   = lo * 128 + ((hi * 16) ^ rswz);           // frag read, kss=0
  const int   fb1   = lo * 128 + ((64 + hi * 16) ^ rswz);      // frag read, kss=1

  float bval[4];
#pragma unroll
  for (int nt = 0; nt < 4; ++nt) bval[nt] = bias[nt * 16 + lo];

  const int B0 = blockIdx.x * ROWS_PER_BLK;
  const int base3 = (wv < 2) ? wv * 96 : 192 + (wv - 2) * 64;
  const int rb0 = B0 + base3;
  const int rb1 = rb0 + 32;
  const bool special = (blockIdx.x == NBLK - 1) && (wv == 2);
  const bool three = (wv < 2) || special;
  const int rb2 = special ? 163840 : rb0 + 64;

#define STAGE_OFFS(P, V0N)                                                     \
  do {                                                                         \
    _Pragma("unroll")                                                          \
    for (int it_ = 0; it_ < 4; ++it_) {                                        \
      const int t_ = it_ * 64 + ln;                                            \
      if (t_ < 224) {                                                          \
        const int jj_ = t_ >> 5;                                               \
        int v_ = (V0N) + (t_ & 31);                                            \
        v_ = (v_ < N_VERT) ? v_ : (N_VERT - 1);                                \
        offsb[wv][P][t_] = hexT[jj_ * N_VERT + v_];                            \
      }                                                                        \
    }                                                                          \
  } while (0)

#define GATH(GS, P, JJ)                                                        \
  do {                                                                         \
    const unsigned int o0_ = offsb[wv][P][(JJ) * 32 + oct];                    \
    const unsigned int o1_ = offsb[wv][P][(JJ) * 32 + 8 + oct];                \
    const unsigned int o2_ = offsb[wv][P][(JJ) * 32 + 16 + oct];               \
    const unsigned int o3_ = offsb[wv][P][(JJ) * 32 + 24 + oct];               \
    GS##0 = *(const s16x8*)(xbase + o0_ + qr16);                               \
    GS##1 = *(const s16x8*)(xbase + o1_ + qr16);                               \
    GS##2 = *(const s16x8*)(xbase + o2_ + qr16);                               \
    GS##3 = *(const s16x8*)(xbase + o3_ + qr16);                               \
  } while (0)

#define DSW(GS)                                                                \
  do {                                                                         \
    *(s16x8*)(bncw)        = GS##0;                                            \
    *(s16x8*)(bncw + 1024) = GS##1;                                            \
    *(s16x8*)(bncw + 2048) = GS##2;                                            \
    *(s16x8*)(bncw + 3072) = GS##3;                                            \
  } while (0)

#define FENCE asm volatile("s_waitcnt lgkmcnt(0)" ::: "memory")

#define MFMA_J(jj)                                                             \
  do {                                                                         \
    const s16x8 S00 = *(const s16x8*)(bnc + fb0);                              \
    const s16x8 S01 = *(const s16x8*)(bnc + fb1);                              \
    const s16x8 S10 = *(const s16x8*)(bnc + 2048 + fb0);                       \
    const s16x8 S11 = *(const s16x8*)(bnc + 2048 + fb1);                       \
    _Pragma("unroll")                                                          \
    for (int nt = 0; nt < 4; ++nt) {                                           \
      const s16x8 bf0 = *(const s16x8*)(Wb + (2 * (jj)) * 4096 + nt * 256);    \
      acc0[nt] = __builtin_amdgcn_mfma_f32_16x16x32_bf16(S00, bf0, acc0[nt], 0, 0, 0); \
      acc1[nt] = __builtin_amdgcn_mfma_f32_16x16x32_bf16(S10, bf0, acc1[nt], 0, 0, 0); \
    }                                                                          \
    _Pragma("unroll")                                                          \
    for (int nt = 0; nt < 4; ++nt) {                                           \
      const s16x8 bf1 = *(const s16x8*)(Wb + (2 * (jj) + 1) * 4096 + nt * 256);\
      acc0[nt] = __builtin_amdgcn_mfma_f32_16x16x32_bf16(S01, bf1, acc0[nt], 0, 0, 0); \
      acc1[nt] = __builtin_amdgcn_mfma_f32_16x16x32_bf16(S11, bf1, acc1[nt], 0, 0, 0); \
    }                                                                          \
  } while (0)

#define STORES(RB)                                                             \
  do {                                                                         \
    _Pragma("unroll")                                                          \
    for (int i = 0; i < 4; ++i) {                                              \
      const int row0 = (RB) + hi * 4 + i;                                      \
      if (row0 < N_VERT) {                                                     \
        float* orow = out + (size_t)row0 * 64;                                 \
        _Pragma("unroll")                                                      \
        for (int nt = 0; nt < 4; ++nt) orow[nt * 16 + lo] = acc0[nt][i] + bval[nt]; \
      }                                                                        \
      const int row1 = (RB) + 16 + hi * 4 + i;                                 \
      if (row1 < N_VERT) {                                                     \
        float* orow = out + (size_t)row1 * 64;                                 \
        _Pragma("unroll")                                                      \
        for (int nt = 0; nt < 4; ++nt) orow[nt * 16 + lo] = acc1[nt][i] + bval[nt]; \
      }                                                                        \
    }                                                                          \
  } while (0)

// One 32-row chunk. Entry: bounce holds j0, GE regs hold j1.
// Gather j+2 in regs || MFMA j || fence || ds_write j+1 (single-buffer WAR-safe).
#define CHUNK(V0, P, GE, GO, HASN, V0N)                                        \
  do {                                                                         \
    if (HASN) STAGE_OFFS((P) ^ 1, V0N);                                        \
    _Pragma("unroll")                                                          \
    for (int nt = 0; nt < 4; ++nt) { acc0[nt] = (f32x4){0,0,0,0}; acc1[nt] = (f32x4){0,0,0,0}; } \
    GATH(GO, P, 2);                                                            \
    MFMA_J(0); FENCE; DSW(GE);                                                 \
    GATH(GE, P, 3);                                                            \
    MFMA_J(1); FENCE; DSW(GO);                                                 \
    GATH(GO, P, 4);                                                            \
    MFMA_J(2); FENCE; DSW(GE);                                                 \
    GATH(GE, P, 5);                                                            \
    MFMA_J(3); FENCE; DSW(GO);                                                 \
    GATH(GO, P, 6);                                                            \
    MFMA_J(4); FENCE; DSW(GE);                                                 \
    if (HASN) GATH(GE, (P) ^ 1, 0);                                            \
    MFMA_J(5); FENCE; DSW(GO);                                                 \
    if (HASN) GATH(GO, (P) ^ 1, 1);                                            \
    MFMA_J(6);                                                                 \
    STORES(V0);                                                                \
    if (HASN) { FENCE; DSW(GE); }                                              \
  } while (0)

  s16x8 gA0, gA1, gA2, gA3, gB0, gB1, gB2, gB3;
  f32x4 acc0[4], acc1[4];

  // prologue: chunk0 offsets; j0 -> bounce; j1 -> regs
  STAGE_OFFS(0, rb0);
  GATH(gA, 0, 0);
  DSW(gA);
  GATH(gB, 0, 1);

  CHUNK(rb0, 0, gB, gA, true, rb1);
  CHUNK(rb1, 1, gA, gB, three, rb2);
  if (three) CHUNK(rb2, 0, gB, gA, false, rb2);

#undef STAGE_OFFS
#undef GATH
#undef DSW
#undef FENCE
#undef MFMA_J
#undef STORES
#undef CHUNK
}

extern "C" void kernel_launch(void* const* d_in, const int* in_sizes, int n_in,
                              void* d_out, int out_size, void* d_ws, size_t ws_size,
                              hipStream_t stream) {
  const float*        x    = (const float*)d_in[0];
  const unsigned int* hexw = (const unsigned int*)d_in[1];
  const float*        W    = (const float*)d_in[2];
  const float*        b    = (const float*)d_in[3];
  float*              out  = (float*)d_out;

  const size_t OFF_WF   = 4096;
  const size_t OFF_HEXT = 65536;
  const size_t OFF_XBF  = 4653568;   // 65536 + 7*N*4 (4587576) rounded up
  const size_t WS_NEED  = OFF_XBF + (size_t)N_VERT * 64 * 2;   // 25,625,344

  if (ws_size >= WS_NEED) {
    int*            flag = (int*)d_ws;
    unsigned short* Wf   = (unsigned short*)((char*)d_ws + OFF_WF);
    unsigned int*   hexT = (unsigned int*)((char*)d_ws + OFF_HEXT);
    unsigned short* xbf  = (unsigned short*)((char*)d_ws + OFF_XBF);
    prep<<<2048, 256, 0, stream>>>(x, hexw, W, Wf, hexT, xbf, flag);
    hexconv8<<<NBLK, 256, 0, stream>>>(xbf, hexT, Wf, b, out);
  } else {
    int* flag = (ws_size >= 4) ? (int*)d_ws : nullptr;
    if (flag) detect64<<<1, 256, 0, stream>>>(hexw, flag);
    hexconv7<0><<<NBLK, 256, 0, stream>>>(x, hexw, W, b, out, flag);
  }
}